// Round 4
// baseline (1034.921 us; speedup 1.0000x reference)
//
#include <hip/hip_runtime.h>
#include <hip/hip_fp16.h>

#define NB 512   // batch
#define NT 512   // time steps
#define NL 126   // labels
#define NS 128   // states (start=126, end=127)

typedef _Float16 h2 __attribute__((ext_vector_type(2)));
typedef _Float16 h8 __attribute__((ext_vector_type(8)));

static __device__ __forceinline__ h2 pk(float a, float b) {
  return __builtin_bit_cast(h2, __builtin_amdgcn_cvt_pkrtz(a, b));
}

// wave64 reduction to lane 63 (identity old=0: ok for add; max needs x>=0)
#define DPP_ADD(x, ctrl, rm) \
  ((x) + __int_as_float(__builtin_amdgcn_update_dpp(0, __float_as_int(x), (ctrl), (rm), 0xf, false)))
#define DPP_MAX(x, ctrl, rm) \
  fmaxf((x), __int_as_float(__builtin_amdgcn_update_dpp(0, __float_as_int(x), (ctrl), (rm), 0xf, false)))
#define WAVE_ADD(x) do { \
  x = DPP_ADD(x, 0x111, 0xf); x = DPP_ADD(x, 0x112, 0xf); \
  x = DPP_ADD(x, 0x114, 0xf); x = DPP_ADD(x, 0x118, 0xf); \
  x = DPP_ADD(x, 0x142, 0xa); x = DPP_ADD(x, 0x143, 0xc); } while (0)
#define WAVE_MAX(x) do { \
  x = DPP_MAX(x, 0x111, 0xf); x = DPP_MAX(x, 0x112, 0xf); \
  x = DPP_MAX(x, 0x114, 0xf); x = DPP_MAX(x, 0x118, 0xf); \
  x = DPP_MAX(x, 0x142, 0xa); x = DPP_MAX(x, 0x143, 0xc); } while (0)

// One 64-thread wave per batch element. Lane l owns columns l and l+64
// entirely (tab in 128 packed-fp16 VGPRs) -> no barriers at all.
__global__ __launch_bounds__(64) void crf_kernel(
    const float* __restrict__ emissions,   // [NB, NT, NL]
    const int*   __restrict__ labels,      // [NB, NT]
    const float* __restrict__ trans,       // [NS, NS]
    float*       __restrict__ out)
{
  const int b = blockIdx.x;
  const int l = threadIdx.x;              // 0..63

  __shared__ __align__(16) h2 u_sh[NS];   // entry i = (u_i, u_i) broadcast pair

  const float* em  = emissions + (size_t)b * NT * NL;
  const int*   lab = labels + b * NT;

  // ---- per-column maxes tau (kept exact, fp32) ----
  float tau0 = -3.0e38f, tau1 = -3.0e38f;
  for (int i = 0; i < NS; i++) {
    tau0 = fmaxf(tau0, trans[i * NS + l]);
    tau1 = fmaxf(tau1, trans[i * NS + l + 64]);
  }
  // ---- tab[i] = ( exp(T[i][l]-tau0), exp(T[i][l+64]-tau1) ) packed fp16 ----
  h2 tab[NS];
  #pragma unroll
  for (int i = 0; i < NS; i++) {
    float t0 = __expf(trans[i * NS + l] - tau0);
    float t1 = __expf(trans[i * NS + l + 64] - tau1);
    tab[i] = pk(t0, t1);
  }

  // ---- gold path partial (8 timesteps per lane) ----
  float realp = 0.f;
  #pragma unroll
  for (int k = 0; k < NT / 64; k++) {
    int t  = l + k * 64;
    int lt = lab[t];
    int nx = (t + 1 < NT) ? lab[t + 1] : (NL + 1);
    realp += em[t * NL + lt] + trans[lt * NS + nx];
  }
  if (l == 0) realp += trans[NL * NS + lab[0]];

  // ---- init: u = delta at state 126 ----
  const h2 zz = {(_Float16)0.f, (_Float16)0.f};
  const h2 oo = {(_Float16)1.f, (_Float16)1.f};
  u_sh[l]      = zz;
  u_sh[l + 64] = (l + 64 == NL) ? oo : zz;

  float Q = 0.f, C = 0.f;
  float em0c = em[l];
  float em1c = (l + 64 < NL) ? em[l + 64] : 0.f;
  float w0 = 0.f, w1 = 0.f, rW = 1.f;

  for (int t = 0; t <= NT; t++) {
    // prefetch next step's emissions (latency covered by inner loop)
    float em0n = 0.f, em1n = 0.f;
    if (t < NT - 1) {
      em0n = em[(t + 1) * NL + l];
      if (l + 64 < NL) em1n = em[(t + 1) * NL + l + 64];
    }

    // inner: full columns l and l+64 (packed), h = colmax, s = colsum
    h2 hA = zz, hB = zz, hC = zz, hD = zz;
    h2 sA = zz, sB = zz, sC = zz, sD = zz;
    const h8* up = (const h8*)u_sh;
    #pragma unroll
    for (int k = 0; k < 32; k++) {
      h8 uu = up[k];                       // rows 4k..4k+3, broadcast read
      h2 q0 = __builtin_shufflevector(uu, uu, 0, 1);
      h2 q1 = __builtin_shufflevector(uu, uu, 2, 3);
      h2 q2 = __builtin_shufflevector(uu, uu, 4, 5);
      h2 q3 = __builtin_shufflevector(uu, uu, 6, 7);
      h2 p0 = q0 * tab[4 * k + 0];
      h2 p1 = q1 * tab[4 * k + 1];
      h2 p2 = q2 * tab[4 * k + 2];
      h2 p3 = q3 * tab[4 * k + 3];
      hA = __builtin_elementwise_max(hA, p0);
      hB = __builtin_elementwise_max(hB, p1);
      hC = __builtin_elementwise_max(hC, p2);
      hD = __builtin_elementwise_max(hD, p3);
      sA += p0; sB += p1; sC += p2; sD += p3;
    }
    h2 hv = __builtin_elementwise_max(__builtin_elementwise_max(hA, hB),
                                      __builtin_elementwise_max(hC, hD));
    h2 sv = (sA + sB) + (sC + sD);

    float h0 = fmaxf((float)hv.x, 1e-30f);
    float h1 = fmaxf((float)hv.y, 1e-30f);
    float s0 = (float)sv.x, s1 = (float)sv.y;
    float contrib = s0 * __builtin_amdgcn_rcpf(h0)
                  + s1 * __builtin_amdgcn_rcpf(h1);

    // g_j = exp(obs_j + tau_j)  (tau INSIDE — per-column; zeroes cols 126/127)
    float g0, g1;
    if (t < NT) {
      g0 = __expf(em0c + tau0);
      g1 = (l + 64 < NL) ? __expf(em1c + tau1) : 0.f;
    } else {
      g0 = 0.f;
      g1 = (l == 63) ? __expf(tau1) : 0.f;   // end state obs=0
    }
    w0 = h0 * g0;
    w1 = h1 * g1;

    float c  = contrib;
    float wm = fmaxf(w0, w1);
    WAVE_ADD(c);
    WAVE_MAX(wm);
    float S = __int_as_float(__builtin_amdgcn_readlane(__float_as_int(c),  63));
    float W = __int_as_float(__builtin_amdgcn_readlane(__float_as_int(wm), 63));

    rW = __builtin_amdgcn_rcpf(W);
    C += __logf(S);
    Q += __logf(W);

    float u0 = w0 * rW, u1 = w1 * rW;
    u_sh[l]      = pk(u0, u0);
    u_sh[l + 64] = pk(u1, u1);

    em0c = em0n; em1c = em1n;
  }

  // ---- total = Q + C + log(sum u); accumulate out += total - real ----
  float su = (w0 + w1) * rW;
  WAVE_ADD(su);
  WAVE_ADD(realp);
  if (l == 63) {
    float total = Q + C + __logf(su);
    atomicAdd(out, total - realp);
  }
}

extern "C" void kernel_launch(void* const* d_in, const int* in_sizes, int n_in,
                              void* d_out, int out_size, void* d_ws, size_t ws_size,
                              hipStream_t stream) {
  const float* em  = (const float*)d_in[0];
  const int*   lab = (const int*)d_in[1];
  const float* tr  = (const float*)d_in[2];
  (void)hipMemsetAsync(d_out, 0, sizeof(float), stream);
  crf_kernel<<<NB, 64, 0, stream>>>(em, lab, tr, (float*)d_out);
}

// Round 5
// 859.196 us; speedup vs baseline: 1.2045x; 1.2045x over previous
//
#include <hip/hip_runtime.h>
#include <hip/hip_fp16.h>

#define NB 512   // batch
#define NT 512   // time steps
#define NL 126   // labels
#define NS 128   // states (start=126, end=127)

typedef _Float16 h2 __attribute__((ext_vector_type(2)));
typedef _Float16 h8 __attribute__((ext_vector_type(8)));
typedef __fp16   f2 __attribute__((ext_vector_type(2)));

static __device__ __forceinline__ h2 pk(float a, float b) {
  return __builtin_bit_cast(h2, __builtin_amdgcn_cvt_pkrtz(a, b));
}

static __device__ __forceinline__ float fdot2(h2 a, h2 b, float c) {
#if __has_builtin(__builtin_amdgcn_fdot2)
  return __builtin_amdgcn_fdot2(__builtin_bit_cast(f2, a),
                                __builtin_bit_cast(f2, b), c, false);
#else
  return c + (float)a.x * (float)b.x + (float)a.y * (float)b.y;
#endif
}

// wave64 reduction to lane 63 (identity old=0: ok for add; max needs x>=0)
#define DPP_ADD(x, ctrl, rm) \
  ((x) + __int_as_float(__builtin_amdgcn_update_dpp(0, __float_as_int(x), (ctrl), (rm), 0xf, false)))
#define DPP_MAX(x, ctrl, rm) \
  fmaxf((x), __int_as_float(__builtin_amdgcn_update_dpp(0, __float_as_int(x), (ctrl), (rm), 0xf, false)))
#define WAVE_ADD(x) do { \
  x = DPP_ADD(x, 0x111, 0xf); x = DPP_ADD(x, 0x112, 0xf); \
  x = DPP_ADD(x, 0x114, 0xf); x = DPP_ADD(x, 0x118, 0xf); \
  x = DPP_ADD(x, 0x142, 0xa); x = DPP_ADD(x, 0x143, 0xc); } while (0)
#define WAVE_MAX(x) do { \
  x = DPP_MAX(x, 0x111, 0xf); x = DPP_MAX(x, 0x112, 0xf); \
  x = DPP_MAX(x, 0x114, 0xf); x = DPP_MAX(x, 0x118, 0xf); \
  x = DPP_MAX(x, 0x142, 0xa); x = DPP_MAX(x, 0x143, 0xc); } while (0)

// One 128-thread block (2 waves) per batch element. Thread j owns column j
// fully: tab = 64 packed-fp16 row-pair VGPRs. Cross-wave traffic per step is
// two scalars per wave; both waves do identical (symmetric) work.
__global__ __launch_bounds__(128) void crf_kernel(
    const float* __restrict__ emissions,   // [NB, NT, NL]
    const int*   __restrict__ labels,      // [NB, NT]
    const float* __restrict__ trans,       // [NS, NS]
    float*       __restrict__ out)
{
  const int b   = blockIdx.x;
  const int j   = threadIdx.x;            // column 0..127
  const int ln  = j & 63;
  const int wid = j >> 6;

  __shared__ __align__(16) _Float16 u_sh[NS];  // u[i], row-major
  __shared__ float scal_s[2], scal_w[2], fin[4];

  const float* em  = emissions + (size_t)b * NT * NL;
  const int*   lab = labels + b * NT;

  // ---- per-column max tau_j (exact fp32) ----
  float tau = -3.0e38f;
  for (int i = 0; i < NS; i++) tau = fmaxf(tau, trans[i * NS + j]);

  // ---- tab[k] = ( exp(T[2k][j]-tau), exp(T[2k+1][j]-tau) ), row pairs ----
  h2 tab[64];
  #pragma unroll
  for (int k = 0; k < 64; k++) {
    float t0 = __expf(trans[(2 * k)     * NS + j] - tau);
    float t1 = __expf(trans[(2 * k + 1) * NS + j] - tau);
    tab[k] = pk(t0, t1);
  }

  // ---- gold path partial (4 timesteps per thread) ----
  float realp = 0.f;
  #pragma unroll
  for (int q = 0; q < NT / 128; q++) {
    int t  = j + q * 128;
    int lt = lab[t];
    int nx = (t + 1 < NT) ? lab[t + 1] : (NL + 1);
    realp += em[t * NL + lt] + trans[lt * NS + nx];
  }
  if (j == 0) realp += trans[NL * NS + lab[0]];

  // ---- init: u = delta at start state ----
  u_sh[j] = (_Float16)((j == NL) ? 1.f : 0.f);
  float Q = 0.f, C = 0.f;
  float emc = (j < NL) ? em[j] : 0.f;
  float w = 0.f, rW = 1.f;
  __syncthreads();

  const h2 zz = {(_Float16)0.f, (_Float16)0.f};

  for (int t = 0; t <= NT; t++) {
    // g_j = exp(obs_j + tau_j): off the u-critical-chain (emc prefetched)
    float obsv;
    if (t < NT) obsv = (j < NL) ? emc : -1000.f;
    else        obsv = (j == NL + 1) ? 0.f : -1000.f;
    float g = __expf(obsv + tau);
    if (t < NT - 1 && j < NL) emc = em[(t + 1) * NL + j];  // prefetch

    // full column j: h = max_i u_i*tab_i, s = sum_i u_i*tab_i (fp32 dot2)
    h2 hA = zz, hB = zz, hC = zz, hD = zz;
    float sA = 0.f, sB = 0.f, sC = 0.f, sD = 0.f;
    const h8* up = (const h8*)u_sh;
    #pragma unroll
    for (int k = 0; k < 16; k++) {
      h8 uu = up[k];                      // rows 8k..8k+7, broadcast read
      h2 q0 = __builtin_shufflevector(uu, uu, 0, 1);
      h2 q1 = __builtin_shufflevector(uu, uu, 2, 3);
      h2 q2 = __builtin_shufflevector(uu, uu, 4, 5);
      h2 q3 = __builtin_shufflevector(uu, uu, 6, 7);
      h2 p0 = q0 * tab[4 * k + 0];
      h2 p1 = q1 * tab[4 * k + 1];
      h2 p2 = q2 * tab[4 * k + 2];
      h2 p3 = q3 * tab[4 * k + 3];
      hA = __builtin_elementwise_max(hA, p0);
      hB = __builtin_elementwise_max(hB, p1);
      hC = __builtin_elementwise_max(hC, p2);
      hD = __builtin_elementwise_max(hD, p3);
      sA = fdot2(q0, tab[4 * k + 0], sA);
      sB = fdot2(q1, tab[4 * k + 1], sB);
      sC = fdot2(q2, tab[4 * k + 2], sC);
      sD = fdot2(q3, tab[4 * k + 3], sD);
    }
    h2 hv = __builtin_elementwise_max(__builtin_elementwise_max(hA, hB),
                                      __builtin_elementwise_max(hC, hD));
    float h = fmaxf(fmaxf((float)hv.x, (float)hv.y), 1e-30f);
    float s = (sA + sB) + (sC + sD);
    float contrib = s * __builtin_amdgcn_rcpf(h);
    w = h * g;

    // per-wave reduce, then 2-scalar cross-wave exchange
    float cS = contrib, cW = w;
    WAVE_ADD(cS);
    WAVE_MAX(cW);
    if (ln == 63) { scal_s[wid] = cS; scal_w[wid] = cW; }
    __syncthreads();                      // barrier A
    float S = scal_s[0] + scal_s[1];
    float W = fmaxf(scal_w[0], scal_w[1]);
    rW = __builtin_amdgcn_rcpf(W);
    C += __logf(S);                       // uniform across threads
    Q += __logf(W);
    u_sh[j] = (_Float16)(w * rW);         // ds_write_b16, 2-way free
    __syncthreads();                      // barrier B
  }

  // ---- total = Q + C + log(sum u); out += total - real ----
  float su = w * rW;
  WAVE_ADD(su);
  WAVE_ADD(realp);
  if (ln == 63) { fin[wid] = su; fin[2 + wid] = realp; }
  __syncthreads();
  if (j == 0) {
    float total = Q + C + __logf(fin[0] + fin[1]);
    atomicAdd(out, total - (fin[2] + fin[3]));
  }
}

extern "C" void kernel_launch(void* const* d_in, const int* in_sizes, int n_in,
                              void* d_out, int out_size, void* d_ws, size_t ws_size,
                              hipStream_t stream) {
  const float* em  = (const float*)d_in[0];
  const int*   lab = (const int*)d_in[1];
  const float* tr  = (const float*)d_in[2];
  (void)hipMemsetAsync(d_out, 0, sizeof(float), stream);
  crf_kernel<<<NB, 128, 0, stream>>>(em, lab, tr, (float*)d_out);
}

// Round 6
// 842.525 us; speedup vs baseline: 1.2284x; 1.0198x over previous
//
#include <hip/hip_runtime.h>
#include <hip/hip_fp16.h>

#define NB 512   // batch
#define NT 512   // time steps
#define NL 126   // labels
#define NS 128   // states (start=126, end=127)
#define SIGMA 0.0625f   // lagged-normalizer target scale (1/16)

typedef _Float16 h2 __attribute__((ext_vector_type(2)));
typedef _Float16 h8 __attribute__((ext_vector_type(8)));

static __device__ __forceinline__ h2 pk(float a, float b) {
  return __builtin_bit_cast(h2, __builtin_amdgcn_cvt_pkrtz(a, b));
}

// wave64 add-reduction to lane 63 (old=0 identity)
#define DPP_ADD(x, ctrl, rm) \
  ((x) + __int_as_float(__builtin_amdgcn_update_dpp(0, __float_as_int(x), (ctrl), (rm), 0xf, false)))
#define WAVE_ADD(x) do { \
  x = DPP_ADD(x, 0x111, 0xf); x = DPP_ADD(x, 0x112, 0xf); \
  x = DPP_ADD(x, 0x114, 0xf); x = DPP_ADD(x, 0x118, 0xf); \
  x = DPP_ADD(x, 0x142, 0xa); x = DPP_ADD(x, 0x143, 0xc); } while (0)

// 128 threads (2 waves) per batch element; thread j owns column j fully.
// Single barrier per step: v double-buffered, normalizer Z lagged one step,
// all reductions/logs off the v-critical-path.
__global__ __launch_bounds__(128, 1) void crf_kernel(
    const float* __restrict__ emissions,   // [NB, NT, NL]
    const int*   __restrict__ labels,      // [NB, NT]
    const float* __restrict__ trans,       // [NS, NS]
    float*       __restrict__ out)
{
  const int b   = blockIdx.x;
  const int j   = threadIdx.x;            // column 0..127
  const int ln  = j & 63;
  const int wid = j >> 6;

  __shared__ __align__(16) _Float16 u_sh[2 * NS];  // ping-pong v buffers
  __shared__ float sPart[2][2], zPart[2][2], fin[4];

  const float* em  = emissions + (size_t)b * NT * NL;
  const int*   lab = labels + b * NT;

  // ---- per-column max tau_j (exact fp32) ----
  float tau = -3.0e38f;
  for (int i = 0; i < NS; i++) tau = fmaxf(tau, trans[i * NS + j]);

  // ---- tab[k] = ( exp(T[2k][j]-tau), exp(T[2k+1][j]-tau) ) row pairs ----
  h2 tab[64];
  #pragma unroll
  for (int k = 0; k < 64; k++) {
    float t0 = __expf(trans[(2 * k)     * NS + j] - tau);
    float t1 = __expf(trans[(2 * k + 1) * NS + j] - tau);
    tab[k] = pk(t0, t1);
  }

  // ---- gold path partial ----
  float realp = 0.f;
  #pragma unroll
  for (int q = 0; q < NT / 128; q++) {
    int t  = j + q * 128;
    int lt = lab[t];
    int nx = (t + 1 < NT) ? lab[t + 1] : (NL + 1);
    realp += em[t * NL + lt] + trans[lt * NS + nx];
  }
  if (j == 0) realp += trans[NL * NS + lab[0]];

  // ---- init: v = delta at start state, in buffer 0 ----
  u_sh[j]      = (_Float16)((j == NL) ? 1.f : 0.f);
  u_sh[NS + j] = (_Float16)0.f;
  float Q = 0.f, C = 0.f;
  // rolling 2-deep emission prefetch
  float emc = (j < NL) ? em[j] : 0.f;
  float emn = (j < NL) ? em[NL + j] : 0.f;
  __syncthreads();

  const h2 zz = {(_Float16)0.f, (_Float16)0.f};

  for (int t = 0; t <= NT; t++) {
    // ---- off-path: lagged scalars from step t-1 (slot t&1) ----
    float r;
    if (t > 0) {
      float S = sPart[t & 1][0] + sPart[t & 1][1];
      float Z = zPart[t & 1][0] + zPart[t & 1][1];
      C += __logf(S);
      Q += __logf(Z);
      r = SIGMA * __builtin_amdgcn_rcpf(Z);
    } else {
      r = SIGMA;                      // Z(init) = 1
    }

    // ---- off-path: g_j = exp(obs_j + tau_j) from prefetched emission ----
    float obsv;
    if (t < NT) obsv = (j < NL) ? emc : -1000.f;
    else        obsv = (j == NL + 1) ? 0.f : -1000.f;
    float g = __expf(obsv + tau);
    float emf = (t + 2 < NT && j < NL) ? em[(t + 2) * NL + j] : 0.f;
    emc = emn; emn = emf;

    // ---- critical path: full column j, packed fp16 only ----
    h2 hA = zz, hB = zz, hC = zz, hD = zz;
    h2 sA = zz, sB = zz, sC = zz, sD = zz;
    const h8* up = (const h8*)(u_sh + (t & 1) * NS);
    #pragma unroll
    for (int k = 0; k < 16; k++) {
      h8 uu = up[k];                  // rows 8k..8k+7, broadcast b128
      h2 q0 = __builtin_shufflevector(uu, uu, 0, 1);
      h2 q1 = __builtin_shufflevector(uu, uu, 2, 3);
      h2 q2 = __builtin_shufflevector(uu, uu, 4, 5);
      h2 q3 = __builtin_shufflevector(uu, uu, 6, 7);
      h2 p0 = q0 * tab[4 * k + 0];
      h2 p1 = q1 * tab[4 * k + 1];
      h2 p2 = q2 * tab[4 * k + 2];
      h2 p3 = q3 * tab[4 * k + 3];
      hA = __builtin_elementwise_max(hA, p0);
      hB = __builtin_elementwise_max(hB, p1);
      hC = __builtin_elementwise_max(hC, p2);
      hD = __builtin_elementwise_max(hD, p3);
      sA += p0; sB += p1; sC += p2; sD += p3;
    }
    h2 hv = __builtin_elementwise_max(__builtin_elementwise_max(hA, hB),
                                      __builtin_elementwise_max(hC, hD));
    h2 sv = (sA + sB) + (sC + sD);
    float h = fmaxf(fmaxf((float)hv.x, (float)hv.y), 1e-30f);
    float s = (float)sv.x + (float)sv.y;

    float w = h * g;
    float v = w * r;
    u_sh[((t + 1) & 1) * NS + j] = (_Float16)v;   // ds_write_b16

    // ---- off-path: reduce contrib and v for next step's scalars ----
    float contrib = s * __builtin_amdgcn_rcpf(h);
    float cS = contrib, cV = v;
    WAVE_ADD(cS);
    WAVE_ADD(cV);
    if (ln == 63) {
      sPart[(t + 1) & 1][wid] = cS;
      zPart[(t + 1) & 1][wid] = cV;
    }
    __syncthreads();                  // the ONLY barrier per step
  }

  // ---- final scalars of step NT (slot (NT+1)&1 = 1) ----
  float S = sPart[1][0] + sPart[1][1];
  float Z = zPart[1][0] + zPart[1][1];
  C += __logf(S);
  Q += __logf(Z);                     // = log sum(v_final)

  // total = C + Q + (NT+1)*log(1/SIGMA)
  const float CONST = (float)(NT + 1) * 2.772588722f;  // log 16

  WAVE_ADD(realp);
  if (ln == 63) fin[wid] = realp;
  __syncthreads();
  if (j == 0) {
    float total = C + Q + CONST;
    atomicAdd(out, total - (fin[0] + fin[1]));
  }
}

extern "C" void kernel_launch(void* const* d_in, const int* in_sizes, int n_in,
                              void* d_out, int out_size, void* d_ws, size_t ws_size,
                              hipStream_t stream) {
  const float* em  = (const float*)d_in[0];
  const int*   lab = (const int*)d_in[1];
  const float* tr  = (const float*)d_in[2];
  (void)hipMemsetAsync(d_out, 0, sizeof(float), stream);
  crf_kernel<<<NB, 128, 0, stream>>>(em, lab, tr, (float*)d_out);
}

// Round 7
// 634.391 us; speedup vs baseline: 1.6314x; 1.3281x over previous
//
#include <hip/hip_runtime.h>
#include <hip/hip_fp16.h>

#define NB 512   // batch
#define NT 512   // time steps
#define NL 126   // labels
#define NS 128   // states (start=126, end=127)
#define SIGMA 0.0625f   // lagged-normalizer target scale (1/16)

typedef _Float16 h2 __attribute__((ext_vector_type(2)));

static __device__ __forceinline__ int pk_from(float a, float b) {
  return __builtin_bit_cast(int, __builtin_amdgcn_cvt_pkrtz(a, b));
}
// guaranteed-packed fp16 ops on int-carried pairs
static __device__ __forceinline__ int pkmul(int a, int b) {
  int d; asm("v_pk_mul_f16 %0, %1, %2" : "=v"(d) : "v"(a), "v"(b)); return d;
}
static __device__ __forceinline__ int pkmax(int a, int b) {
  int d; asm("v_pk_max_f16 %0, %1, %2" : "=v"(d) : "v"(a), "v"(b)); return d;
}
static __device__ __forceinline__ int pkadd(int a, int b) {
  int d; asm("v_pk_add_f16 %0, %1, %2" : "=v"(d) : "v"(a), "v"(b)); return d;
}
// swap lane pairs (0<->1, 2<->3): quad_perm [1,0,3,2]
static __device__ __forceinline__ int dppswap(int x) {
  return __builtin_amdgcn_update_dpp(0, x, 0xB1, 0xf, 0xf, false);
}

// wave64 add-reduction to lane 63 (old=0 identity)
#define DPP_ADD(x, ctrl, rm) \
  ((x) + __int_as_float(__builtin_amdgcn_update_dpp(0, __float_as_int(x), (ctrl), (rm), 0xf, false)))
#define WAVE_ADD(x) do { \
  x = DPP_ADD(x, 0x111, 0xf); x = DPP_ADD(x, 0x112, 0xf); \
  x = DPP_ADD(x, 0x114, 0xf); x = DPP_ADD(x, 0x118, 0xf); \
  x = DPP_ADD(x, 0x142, 0xa); x = DPP_ADD(x, 0x143, 0xc); } while (0)

// 256 threads (4 waves) per batch element. Lane pair (2c,2c+1) of wave w owns
// column 32w+c: each lane covers 64 rows (tab = 32 packed VGPRs). Single
// barrier per step; normalizer Z lagged one step (R5 math, absmax 0.0).
__global__ __launch_bounds__(256) void crf_kernel(
    const float* __restrict__ emissions,   // [NB, NT, NL]
    const int*   __restrict__ labels,      // [NB, NT]
    const float* __restrict__ trans,       // [NS, NS]
    float*       __restrict__ out)
{
  const int b   = blockIdx.x;
  const int tid = threadIdx.x;
  const int wv  = tid >> 6;              // wave 0..3
  const int ln  = tid & 63;
  const int col = (wv << 5) | (ln >> 1); // column 0..127
  const int rh  = ln & 1;                // row half: rows [rh*64, rh*64+64)

  __shared__ __align__(16) _Float16 u_sh[2 * NS];   // ping-pong v buffers
  __shared__ __align__(16) float sPart[2][4];
  __shared__ __align__(16) float zPart[2][4];
  __shared__ float fin[4];

  const float* em  = emissions + (size_t)b * NT * NL;
  const int*   lab = labels + b * NT;

  // ---- per-column max tau (exact fp32) ----
  float tau = -3.0e38f;
  for (int i = 0; i < NS; i++) tau = fmaxf(tau, trans[i * NS + col]);

  // ---- tab[k] = rows (rh*64+2k, rh*64+2k+1) of exp(T[.][col]-tau) ----
  int tab[32];
  #pragma unroll
  for (int k = 0; k < 32; k++) {
    int row = rh * 64 + 2 * k;
    float t0 = __expf(trans[row * NS + col] - tau);
    float t1 = __expf(trans[(row + 1) * NS + col] - tau);
    tab[k] = pk_from(t0, t1);
  }

  // ---- gold path partial (2 timesteps per thread) ----
  float realp = 0.f;
  #pragma unroll
  for (int q = 0; q < NT / 256; q++) {
    int t  = tid + q * 256;
    int lt = lab[t];
    int nx = (t + 1 < NT) ? lab[t + 1] : (NL + 1);
    realp += em[t * NL + lt] + trans[lt * NS + nx];
  }
  if (tid == 0) realp += trans[NL * NS + lab[0]];

  // ---- init: v = delta at start state, buffer 0 ----
  if (tid < NS) {
    u_sh[tid]      = (_Float16)((tid == NL) ? 1.f : 0.f);
    u_sh[NS + tid] = (_Float16)0.f;
  }
  float Q = 0.f, Cc = 0.f;
  float emc = (col < NL) ? em[col] : 0.f;        // rolling 2-deep prefetch
  float emn = (col < NL) ? em[NL + col] : 0.f;
  __syncthreads();

  for (int t = 0; t <= NT; t++) {
    // ---- off-path: lagged scalars from step t-1 (slot t&1) ----
    float r;
    if (t > 0) {
      const float4 sp = *(const float4*)sPart[t & 1];
      const float4 zp = *(const float4*)zPart[t & 1];
      float S = 0.5f * ((sp.x + sp.y) + (sp.z + sp.w));  // 0.5: pair-dup
      float Z = 0.5f * ((zp.x + zp.y) + (zp.z + zp.w));
      Cc += __logf(S);
      Q  += __logf(Z);
      r = SIGMA * __builtin_amdgcn_rcpf(Z);
    } else {
      r = SIGMA;                       // Z(init) = 1
    }

    // ---- off-path: g = exp(obs + tau) from prefetched emission ----
    float obsv;
    if (t < NT) obsv = (col < NL) ? emc : -1000.f;
    else        obsv = (col == NL + 1) ? 0.f : -1000.f;
    float g = __expf(obsv + tau);
    float emf = (t + 2 < NT && col < NL) ? em[(t + 2) * NL + col] : 0.f;
    emc = emn; emn = emf;

    // ---- critical path: 64 rows of column col, packed fp16 asm ----
    const int4* up = (const int4*)(u_sh + (t & 1) * NS) + rh * 8;
    int hA = 0, hB = 0, hC = 0, hD = 0;
    int sA = 0, sB = 0, sC = 0, sD = 0;
    #pragma unroll
    for (int kk = 0; kk < 8; kk++) {
      int4 uu = up[kk];                // rows rh*64+8kk..+7, 2-addr broadcast
      int m0 = pkmul(uu.x, tab[4 * kk + 0]);
      int m1 = pkmul(uu.y, tab[4 * kk + 1]);
      int m2 = pkmul(uu.z, tab[4 * kk + 2]);
      int m3 = pkmul(uu.w, tab[4 * kk + 3]);
      hA = pkmax(hA, m0); hB = pkmax(hB, m1);
      hC = pkmax(hC, m2); hD = pkmax(hD, m3);
      sA = pkadd(sA, m0); sB = pkadd(sB, m1);
      sC = pkadd(sC, m2); sD = pkadd(sD, m3);
    }
    int hv = pkmax(pkmax(hA, hB), pkmax(hC, hD));
    int sv = pkadd(pkadd(sA, sB), pkadd(sC, sD));
    hv = pkmax(hv, dppswap(hv));       // combine row halves across lane pair
    sv = pkadd(sv, dppswap(sv));
    h2 hh = __builtin_bit_cast(h2, hv);
    h2 ss = __builtin_bit_cast(h2, sv);
    float h = fmaxf(fmaxf((float)hh.x, (float)hh.y), 1e-30f);
    float s = (float)ss.x + (float)ss.y;

    float w = h * g;
    float v = w * r;
    u_sh[((t + 1) & 1) * NS + col] = (_Float16)v;  // both pair-lanes, same value

    // ---- off-path: reductions for next step's scalars ----
    float contrib = s * __builtin_amdgcn_rcpf(h);
    float cS = contrib, cV = v;
    WAVE_ADD(cS);
    WAVE_ADD(cV);
    if (ln == 63) {
      sPart[(t + 1) & 1][wv] = cS;
      zPart[(t + 1) & 1][wv] = cV;
    }
    __syncthreads();                   // the ONLY barrier per step
  }

  // ---- final scalars of step NT (slot (NT+1)&1 = 1) ----
  {
    const float4 sp = *(const float4*)sPart[1];
    const float4 zp = *(const float4*)zPart[1];
    float S = 0.5f * ((sp.x + sp.y) + (sp.z + sp.w));
    float Z = 0.5f * ((zp.x + zp.y) + (zp.z + zp.w));
    Cc += __logf(S);
    Q  += __logf(Z);
  }

  // total = Cc + Q + (NT+1)*log(1/SIGMA)
  WAVE_ADD(realp);
  if (ln == 63) fin[wv] = realp;
  __syncthreads();
  if (tid == 0) {
    const float CONST = 513.f * 2.772588722f;   // (NT+1) * log 16
    float total = Cc + Q + CONST;
    atomicAdd(out, total - ((fin[0] + fin[1]) + (fin[2] + fin[3])));
  }
}

extern "C" void kernel_launch(void* const* d_in, const int* in_sizes, int n_in,
                              void* d_out, int out_size, void* d_ws, size_t ws_size,
                              hipStream_t stream) {
  const float* em  = (const float*)d_in[0];
  const int*   lab = (const int*)d_in[1];
  const float* tr  = (const float*)d_in[2];
  (void)hipMemsetAsync(d_out, 0, sizeof(float), stream);
  crf_kernel<<<NB, 256, 0, stream>>>(em, lab, tr, (float*)d_out);
}